// Round 13
// baseline (177.946 us; speedup 1.0000x reference)
//
#include <hip/hip_runtime.h>

typedef float        f32x4  __attribute__((ext_vector_type(4)));
typedef float        f32x16 __attribute__((ext_vector_type(16)));
typedef unsigned int u32x4  __attribute__((ext_vector_type(4)));
typedef unsigned int u32x2  __attribute__((ext_vector_type(2)));
typedef int          i32x2  __attribute__((ext_vector_type(2)));
typedef __bf16       bf16x8 __attribute__((ext_vector_type(8)));

#define DEVFN static __device__ __forceinline__

DEVFN unsigned cvtpk(float a, float b){       // bf16 pack
  unsigned r;
  asm("v_cvt_pk_bf16_f32 %0, %1, %2" : "=v"(r) : "v"(a), "v"(b));
  return r;
}
DEVFN float exp2_hw(float x){
  float r;
  asm("v_exp_f32 %0, %1" : "=v"(r) : "v"(x));
  return r;
}
DEVFN bf16x8 as_bf(u32x4 v){ union{u32x4 u; bf16x8 b;} x; x.u=v; return x.b; }

DEVFN unsigned char f2fp8(float v){           // scalar f32 -> e4m3 byte
  int r = __builtin_amdgcn_cvt_pk_fp8_f32(v, v, 0, false);
  return (unsigned char)(r & 0xff);
}
DEVFN unsigned pk4_fp8(float a, float b, float c, float d){  // bytes [a,b,c,d]
  int r = __builtin_amdgcn_cvt_pk_fp8_f32(a, b, 0, false);
  r = __builtin_amdgcn_cvt_pk_fp8_f32(c, d, r, true);
  return (unsigned)r;
}
DEVFN long mk64(unsigned lo, unsigned hi){
  return (long)(((unsigned long long)hi << 32) | lo);
}

DEVFN void gload16(const char* src, char* lds){
  __builtin_amdgcn_global_load_lds(
      (__attribute__((address_space(1))) void*)src,
      (__attribute__((address_space(3))) void*)lds, 16, 0, 0);
}

// f32 tile frag read with involution XOR swizzle (rows of 128B; XOR bits4-6 by row&7)
DEVFN bf16x8 ldfrag_f32(const char* base, int rel){
  int sw = ((rel>>7)&7)<<4;                   // same row for rel and rel+16
  f32x4 f0 = *(const f32x4*)(base + (rel ^ sw));
  f32x4 f1 = *(const f32x4*)(base + ((rel+16) ^ sw));
  u32x4 p;
  p[0]=cvtpk(f0[0],f0[1]); p[1]=cvtpk(f0[2],f0[3]);
  p[2]=cvtpk(f1[0],f1[1]); p[3]=cvtpk(f1[2],f1[3]);
  return as_bf(p);
}

constexpr int BB = 16, NQ = 2048, NK = 2048, F = 512, D = 256, FV = 512;

// ---------------- projection + row l2norm -> fp8 outputs ----------------
// MODE 0/1 (ND=256): f32 global_load_lds staging, 36KB dbuf, 1 barrier/iter,
//   bf16 cvt at fragment read (pre-swizzled source <-> swizzled read, rule #21).
// MODE 2: R12 path verbatim (bf16 reg-staged sbuf, 2 barriers/iter).
// Epilogues (R12 verbatim): byte-scatter to LDS -> dense coalesced b128 stores.
template<int KD, int ND, int MODE>
DEVFN void proj_body(const float* __restrict__ X, const float* __restrict__ W,
                     unsigned char* __restrict__ Y, float scale,
                     char* sm, float (*wsum)[32], int bid)
{
  constexpr bool TR = (MODE == 2);
  constexpr int NW = ND/4;
  constexpr int AF = TR ? 8 : 2;
  constexpr int BF = TR ? 2 : NW/16;
  constexpr int NIT = KD/32;
  const int tid = threadIdx.x;
  const int lane = tid & 63;
  const int wid = tid >> 6;
  const int q16 = lane & 15;
  const int g = lane >> 4;
  const int row0 = bid * 32;
  const int rX = tid >> 3, cX = (tid & 7) * 4;

  f32x4 z4 = {0.f,0.f,0.f,0.f};
  f32x4 acc[AF][BF];
  #pragma unroll
  for (int i=0;i<AF;i++){
    #pragma unroll
    for (int j=0;j<BF;j++) acc[i][j] = z4;
  }

  if constexpr (!TR){
    // ---- modes 0/1: gload-f32 dbuf pipeline ----
    // buf layout per 36864B: X [32 rows][128B] @0 | W [256 rows][128B] @4096
    #define STAGE01(T, CUR) do{                                               \
      char* xb_ = sm + (CUR)*36864;                                           \
      char* wb_ = xb_ + 4096;                                                 \
      {                                                                       \
        int rel = wid*1024 + lane*16;                                         \
        int ds  = rel ^ (((rel>>7)&7)<<4);                                    \
        int row = ds>>7, cb = ds & 127;                                       \
        gload16((const char*)X + ((size_t)(row0+row)*KD + (T)*32)*4 + cb,     \
                xb_ + rel);                                                   \
      }                                                                       \
      _Pragma("unroll")                                                       \
      for (int j=0;j<8;j++){                                                  \
        int rel = (wid*8+j)*1024 + lane*16;                                   \
        int ds  = rel ^ (((rel>>7)&7)<<4);                                    \
        int row = ds>>7, cb = ds & 127;                                       \
        gload16((const char*)W + ((size_t)row*KD + (T)*32)*4 + cb,            \
                wb_ + rel);                                                   \
      }                                                                       \
    }while(0)

    STAGE01(0, 0);
    __syncthreads();
    for (int t = 0; t < NIT; ++t){
      const int cur = t & 1;
      if (t + 1 < NIT) STAGE01(t+1, cur^1);
      const char* xb = sm + cur*36864;
      const char* wb = xb + 4096;
      bf16x8 a[2], bb[BF];
      #pragma unroll
      for (int mi=0;mi<2;mi++)
        a[mi] = ldfrag_f32(xb, (16*mi+q16)*128 + g*32);
      #pragma unroll
      for (int ni=0;ni<BF;ni++)
        bb[ni] = ldfrag_f32(wb, (wid*NW + 16*ni + q16)*128 + g*32);
      #pragma unroll
      for (int mi=0;mi<2;mi++){
        #pragma unroll
        for (int ni=0;ni<BF;ni++)
          acc[mi][ni] = __builtin_amdgcn_mfma_f32_16x16x32_bf16(a[mi], bb[ni], acc[mi][ni], 0,0,0);
      }
      __syncthreads();   // drains this iter's gloads + buf handoff
    }
    #undef STAGE01
  } else {
    // ---- mode 2: R12 path (bf16 reg-staged single buffer) ----
    f32x4 xr = *(const f32x4*)(X + (size_t)(row0+rX)*KD + cX);
    f32x4 wr[ND/32];
    #pragma unroll
    for (int j=0;j<ND/32;j++)
      wr[j] = *(const f32x4*)(W + (size_t)(j*32+rX)*KD + cX);

    for (int t = 0; t < NIT; ++t){
      char* xb = sm; char* wb = sm + 2560;
      {
        u32x2 p; p[0]=cvtpk(xr[0],xr[1]); p[1]=cvtpk(xr[2],xr[3]);
        *(u32x2*)(xb + rX*80 + cX*2) = p;
      }
      #pragma unroll
      for (int j=0;j<ND/32;j++){
        u32x2 p; p[0]=cvtpk(wr[j][0],wr[j][1]); p[1]=cvtpk(wr[j][2],wr[j][3]);
        *(u32x2*)(wb + (j*32+rX)*80 + cX*2) = p;
      }
      if (t + 1 < NIT){
        int k0n = (t+1)*32;
        xr = *(const f32x4*)(X + (size_t)(row0+rX)*KD + k0n + cX);
        #pragma unroll
        for (int j=0;j<ND/32;j++)
          wr[j] = *(const f32x4*)(W + (size_t)(j*32+rX)*KD + k0n + cX);
      }
      __syncthreads();
      bf16x8 a[8], bb[2];
      #pragma unroll
      for (int ai=0;ai<8;ai++) a[ai] = as_bf(*(const u32x4*)(wb + (wid*NW + 16*ai + q16)*80 + g*16));
      #pragma unroll
      for (int ci=0;ci<2;ci++) bb[ci] = as_bf(*(const u32x4*)(xb + (16*ci+q16)*80 + g*16));
      #pragma unroll
      for (int ai=0;ai<8;ai++){
        #pragma unroll
        for (int ci=0;ci<2;ci++)
          acc[ai][ci] = __builtin_amdgcn_mfma_f32_16x16x32_bf16(a[ai], bb[ci], acc[ai][ci], 0,0,0);
      }
      __syncthreads();
    }
  }

  unsigned char* lds8 = (unsigned char*)sm;

  if constexpr (!TR){
    float part[2][4];
    #pragma unroll
    for (int mi=0;mi<2;mi++){
      #pragma unroll
      for (int r=0;r<4;r++){
        float s=0.f;
        #pragma unroll
        for (int ni=0;ni<BF;ni++){ float v=acc[mi][ni][r]; s += v*v; }
        part[mi][r]=s;
      }
    }
    #pragma unroll
    for (int m=1;m<16;m<<=1){
      #pragma unroll
      for (int mi=0;mi<2;mi++){
        #pragma unroll
        for (int r=0;r<4;r++) part[mi][r] += __shfl_xor(part[mi][r], m);
      }
    }
    __syncthreads();
    if (q16 == 0){
      #pragma unroll
      for (int mi=0;mi<2;mi++){
        #pragma unroll
        for (int r=0;r<4;r++) wsum[wid][16*mi + 4*g + r] = part[mi][r];
      }
    }
    __syncthreads();
    // scatter bytes into LDS [8KB]
    #pragma unroll
    for (int mi=0;mi<2;mi++){
      #pragma unroll
      for (int r=0;r<4;r++){
        int m = 16*mi + 4*g + r;
        float tot = wsum[0][m]+wsum[1][m]+wsum[2][m]+wsum[3][m];
        float inv = scale / fmaxf(sqrtf(tot), 1e-12f);
        #pragma unroll
        for (int ni=0;ni<BF;ni++){
          int col = wid*NW + 16*ni + q16;
          unsigned char vb = f2fp8(acc[mi][ni][r]*inv);
          if constexpr (MODE == 0){
            lds8[m*256 + col] = vb;
          } else {
            int u = col >> 5, dd = col & 31;
            int s = ((dd>>4)<<3) | (dd&7);
            int l = (m & 31) + ((dd>>3)&1)*32;
            lds8[(u*64 + l)*16 + s] = vb;
          }
        }
      }
    }
    __syncthreads();
    // dense coalesced writeout: 8KB = 2 passes x 256 thr x 16B
    unsigned char* dst;
    if constexpr (MODE == 0){
      dst = Y + (size_t)row0*256;
    } else {
      int b2 = row0 >> 11, kt = (row0 & 2047) >> 5;
      dst = Y + (((size_t)b2*64 + kt)*8192);
    }
    #pragma unroll
    for (int pass=0; pass<2; ++pass){
      int off = pass*4096 + tid*16;
      *(u32x4*)(dst + off) = *(const u32x4*)(lds8 + off);
    }
  } else {
    float pp[2];
    #pragma unroll
    for (int ci=0;ci<2;ci++){
      float s=0.f;
      #pragma unroll
      for (int ai=0;ai<8;ai++){
        #pragma unroll
        for (int r=0;r<4;r++){ float v=acc[ai][ci][r]; s += v*v; }
      }
      pp[ci]=s;
    }
    #pragma unroll
    for (int ci=0;ci<2;ci++){
      pp[ci] += __shfl_xor(pp[ci],16);
      pp[ci] += __shfl_xor(pp[ci],32);
    }
    if (lane < 16){ wsum[wid][lane] = pp[0]; wsum[wid][16+lane] = pp[1]; }
    __syncthreads();
    // scatter bytes into LDS [16KB]: addr = (fvb*2+ci)*512 + l31v*16 + q16
    #pragma unroll
    for (int ci=0;ci<2;ci++){
      int m = 16*ci + q16;
      float tot = wsum[0][m]+wsum[1][m]+wsum[2][m]+wsum[3][m];
      float inv = scale / fmaxf(sqrtf(tot), 1e-12f);
      #pragma unroll
      for (int ai=0;ai<8;ai++){
        #pragma unroll
        for (int r=0;r<4;r++){
          int n = wid*NW + 16*ai + 4*g + r;
          int fvb = n >> 5, l31v = n & 31;
          unsigned char vb = f2fp8(acc[ai][ci][r]*inv);
          lds8[(fvb*2 + ci)*512 + l31v*16 + q16] = vb;
        }
      }
    }
    __syncthreads();
    // dense writeout: 16KB in 4 passes x 256 thr x 16B; chunk = 512B
    int b2 = row0 >> 11;
    int kvv = row0 & 2047;
    int t64 = kvv >> 6, hh = (kvv >> 5) & 1;
    unsigned char* vbase = Y + ((size_t)b2*32 + t64)*32768;
    #pragma unroll
    for (int pass=0; pass<4; ++pass){
      int L = pass*4096 + tid*16;
      int c = L >> 9, inner = L & 511;
      unsigned char* dst = vbase + (size_t)(c>>1)*2048 + (c&1)*1024 + hh*512 + inner;
      *(u32x4*)dst = *(const u32x4*)(lds8 + L);
    }
  }
}

__global__ __launch_bounds__(256,2) void proj_all(
    const float* __restrict__ query, const float* __restrict__ key,
    const float* __restrict__ value, const float* __restrict__ WQ,
    const float* __restrict__ WK, const float* __restrict__ WV,
    unsigned char* __restrict__ wq8, unsigned char* __restrict__ k8,
    unsigned char* __restrict__ v8, float sq)
{
  __shared__ __align__(16) char sm[73728];   // modes 0/1: 2x36864 dbuf; mode 2: 43520 sbuf
  __shared__ float wsum[4][32];
  const int bid = blockIdx.x;
  if (bid < 1024){
    proj_body<512,256,0>(query, WQ, wq8, sq,   sm, wsum, bid);
  } else if (bid < 2048){
    proj_body<256,256,1>(key,   WK, k8,  8.0f, sm, wsum, bid - 1024);
  } else {
    proj_body<256,512,2>(value, WV, v8,  8.0f, sm, wsum, bid - 2048);
  }
}

// ---------------- fused attention (v10: fp8 K=16, kv-tile 64, exp-split) --------
// (R10 verbatim — 97.5 us, MfmaUtil 43%, no spill; frozen)
__global__ __launch_bounds__(512,2) void attn_kernel(const float* __restrict__ query,
    const unsigned char* __restrict__ wq8, const unsigned char* __restrict__ k8,
    const unsigned char* __restrict__ v8, float* __restrict__ out)
{
  // K dbuf 2x16K @0 | V dbuf 2x32K @32768 | P 8K @98304. Epilogue reuses 64K.
  __shared__ __align__(16) char smem[106496];
  const int tid = threadIdx.x, lane = tid & 63, wid = tid >> 6;
  const int l31 = lane & 31, h = lane >> 5;
  const int qs = wid & 3, fvh = wid >> 2;
  const int bid = blockIdx.x;
  const int lb = (bid & 7)*32 + (bid >> 3);   // XCD chunk swizzle, 256 = 8*32 bijective
  const int b = lb >> 4;
  const int qblk = lb & 15;
  const int q0 = qblk*128;

  const char* ksrc = (const char*)(k8 + (size_t)b*524288)  + lane*16;
  const char* vsrc = (const char*)(v8 + (size_t)b*1048576) + lane*16;
  char* const pwav = smem + 98304 + qs*2048;   // [s 2][row 8][q 32] dwords

  #define STAGE(T, CUR) do{                                                  \
    gload16(ksrc + (size_t)(T)*16384 + (2*wid  )*1024,                       \
            smem + (CUR)*16384 + (2*wid  )*1024);                            \
    gload16(ksrc + (size_t)(T)*16384 + (2*wid+1)*1024,                       \
            smem + (CUR)*16384 + (2*wid+1)*1024);                            \
    _Pragma("unroll")                                                        \
    for (int i_=0;i_<4;i_++)                                                 \
      gload16(vsrc + (size_t)(T)*32768 + (4*wid+i_)*1024,                    \
              smem + 32768 + (CUR)*32768 + (4*wid+i_)*1024);                 \
  }while(0)

  STAGE(0, 0);

  // Q hoist: fp8 B-frags [16 c][32 q]: lane q=l31, bytes d = c*16 + h*8 ..+8
  unsigned long long qf[16];
  {
    const unsigned char* qb = wq8 + ((size_t)b*NQ + q0 + qs*32 + l31)*D;
    #pragma unroll
    for (int c=0;c<16;c++) qf[c] = *(const unsigned long long*)(qb + c*16 + h*8);
  }

  f32x16 z16;
  #pragma unroll
  for (int i=0;i<16;i++) z16[i]=0.f;
  f32x16 o[8];
  #pragma unroll
  for (int i=0;i<8;i++) o[i]=z16;
  float ssum = 0.f;
  const float c2 = 0.0625f * 1.4426950408889634f / 64.0f;   // temp*log2e/(8*8)

  __syncthreads();

  #define BODY(T, CUR) do{                                                          \
    if ((T) < 31) STAGE((T)+1, (CUR)^1);                                            \
    /* QK on own kv-sub-tile (kt = 2T + fvh) */                                     \
    const char* kb = smem + (CUR)*16384 + fvh*8192;                                 \
    f32x16 S = z16;                                                                 \
    __builtin_amdgcn_s_setprio(1);                                                  \
    _Pragma("unroll")                                                               \
    for (int u=0;u<8;u++){                                                          \
      u32x4 kk = *(const u32x4*)(kb + u*1024 + lane*16);                            \
      S = __builtin_amdgcn_mfma_f32_32x32x16_fp8_fp8(mk64(kk[0],kk[1]),             \
            (long)qf[2*u],   S, 0,0,0);                                             \
      S = __builtin_amdgcn_mfma_f32_32x32x16_fp8_fp8(mk64(kk[2],kk[3]),             \
            (long)qf[2*u+1], S, 0,0,0);                                             \
    }                                                                               \
    __builtin_amdgcn_s_setprio(0);                                                  \
    float p[16];                                                                    \
    _Pragma("unroll")                                                               \
    for (int r=0;r<16;r++) p[r] = exp2_hw(S[r]*c2);                                 \
    {                                                                               \
      float s2a = (p[0]+p[1])+(p[2]+p[3]),  s2b = (p[4]+p[5])+(p[6]+p[7]);          \
      float s2c = (p[8]+p[9])+(p[10]+p[11]), s2d = (p[12]+p[13])+(p[14]+p[15]);     \
      ssum += (s2a+s2b) + (s2c+s2d);                                                \
    }                                                                               \
    /* pack P -> LDS: dword m covers kv_local 8m+4h..+3 ; row = m*2+h */            \
    _Pragma("unroll")                                                               \
    for (int m=0;m<4;m++){                                                          \
      unsigned dw = pk4_fp8(p[4*m],p[4*m+1],p[4*m+2],p[4*m+3]);                     \
      *(unsigned*)(pwav + fvh*1024 + (m*2+h)*128 + l31*4) = dw;                     \
    }                                                                               \
    __syncthreads();   /* P visible; staging (issued at top) drains */              \
    __builtin_amdgcn_s_setprio(1);                                                  \
    _Pragma("unroll")                                                               \
    for (int s=0;s<2;s++){                                                          \
      unsigned lo0 = *(const unsigned*)(pwav + s*1024 + ((0+h)*2  )*128 + l31*4);   \
      unsigned hi0 = *(const unsigned*)(pwav + s*1024 + ((0+h)*2+1)*128 + l31*4);   \
      unsigned lo1 = *(const unsigned*)(pwav + s*1024 + ((2+h)*2  )*128 + l31*4);   \
      unsigned hi1 = *(const unsigned*)(pwav + s*1024 + ((2+h)*2+1)*128 + l31*4);   \
      long B0 = mk64(lo0, hi0), B1 = mk64(lo1, hi1);                                \
      const char* vb = smem + 32768 + (CUR)*32768 + s*16384 + fvh*8192;             \
      _Pragma("unroll")                                                             \
      for (int u=0;u<8;u++){                                                        \
        u32x4 vv = *(const u32x4*)(vb + u*1024 + lane*16);                          \
        o[u] = __builtin_amdgcn_mfma_f32_32x32x16_fp8_fp8(mk64(vv[0],vv[1]), B0,    \
                                                          o[u], 0,0,0);             \
        o[u] = __builtin_amdgcn_mfma_f32_32x32x16_fp8_fp8(mk64(vv[2],vv[3]), B1,    \
                                                          o[u], 0,0,0);             \
      }                                                                             \
    }                                                                               \
    __builtin_amdgcn_s_setprio(0);                                                  \
    __syncthreads();   /* tile handoff; protects P for next write */                \
  }while(0)

  for (int tt = 0; tt < 32; tt += 2){
    BODY(tt,   0);
    BODY(tt+1, 1);
  }
  #undef BODY
  #undef STAGE

  // ssum: + h-partner (in-wave), then + fvh-partner wave (via LDS, post-loop reuse)
  ssum += __shfl_xor(ssum, 32);
  {
    float* sx = (float*)(smem + 98304);
    sx[(qs*2+fvh)*32 + l31] = ssum;
    __syncthreads();
    ssum += sx[(qs*2+(1-fvh))*32 + l31];
  }
  const float inv = 1.f/(8.f*ssum);
  #pragma unroll
  for (int i=0;i<8;i++){
    #pragma unroll
    for (int r=0;r<16;r++) o[i][r] *= inv;
  }

  // epilogue: transpose via LDS [32q][128fv] x2 per qs, +query, store.
  char* wsc = smem + qs*16384;
  union U16 { f32x16 v; f32x4 q4[4]; };
  const int swz = (l31 & 7) << 4;
  #pragma unroll
  for (int phase=0; phase<2; ++phase){
    if (fvh == phase){
      #pragma unroll
      for (int hf=0; hf<2; ++hf){
        #pragma unroll
        for (int fc2=0; fc2<4; ++fc2){
          U16 u; u.v = o[hf*4+fc2];
          #pragma unroll
          for (int k=0;k<4;k++){
            *(f32x4*)(wsc + l31*512 + ((fc2*128 + k*32 + h*16) ^ swz)) = u.q4[k];
          }
        }
        #pragma unroll
        for (int p2=0;p2<16;p2++){
          int qr = p2*2 + h;
          f32x4 v = *(const f32x4*)(wsc + qr*512 + ((l31*16) ^ ((qr&7)<<4)));
          size_t row = (size_t)b*NQ + q0 + qs*32 + qr;
          int col = fvh*256 + hf*128 + l31*4;
          f32x4 qv = *(const f32x4*)(query + row*F + col);
          #pragma unroll
          for (int e=0;e<4;e++) v[e] += qv[e];
          *(f32x4*)(out + row*F + col) = v;
        }
      }
    }
    __syncthreads();
  }
}

extern "C" void kernel_launch(void* const* d_in, const int* in_sizes, int n_in,
                              void* d_out, int out_size, void* d_ws, size_t ws_size,
                              hipStream_t stream)
{
  const float* query = (const float*)d_in[0];
  const float* key   = (const float*)d_in[1];
  const float* value = (const float*)d_in[2];
  const float* WQ    = (const float*)d_in[3];
  const float* WK    = (const float*)d_in[4];
  const float* WV    = (const float*)d_in[5];
  float* out = (float*)d_out;

  unsigned char* wq8 = (unsigned char*)d_ws;                 // [B*NQ][256] fp8, 8MB
  unsigned char* k8  = wq8 + (size_t)BB*NQ*D;                // K frag-image, 8MB
  unsigned char* v8  = k8  + (size_t)BB*NK*D;                // V frag-image, 16MB

  proj_all<<<3072, dim3(256), 0, stream>>>(query, key, value, WQ, WK, WV,
                                           wq8, k8, v8, 8.0f);
  attn_kernel<<<256, dim3(512), 0, stream>>>(query, wq8, k8, v8, out);
}

// Round 14
// 157.726 us; speedup vs baseline: 1.1282x; 1.1282x over previous
//
#include <hip/hip_runtime.h>

typedef float        f32x4  __attribute__((ext_vector_type(4)));
typedef float        f32x16 __attribute__((ext_vector_type(16)));
typedef unsigned int u32x4  __attribute__((ext_vector_type(4)));
typedef unsigned int u32x2  __attribute__((ext_vector_type(2)));
typedef int          i32x2  __attribute__((ext_vector_type(2)));
typedef __bf16       bf16x8 __attribute__((ext_vector_type(8)));

#define DEVFN static __device__ __forceinline__

DEVFN unsigned cvtpk(float a, float b){       // bf16 pack (proj staging)
  unsigned r;
  asm("v_cvt_pk_bf16_f32 %0, %1, %2" : "=v"(r) : "v"(a), "v"(b));
  return r;
}
DEVFN float exp2_hw(float x){
  float r;
  asm("v_exp_f32 %0, %1" : "=v"(r) : "v"(x));
  return r;
}
DEVFN bf16x8 as_bf(u32x4 v){ union{u32x4 u; bf16x8 b;} x; x.u=v; return x.b; }

DEVFN unsigned char f2fp8(float v){           // scalar f32 -> e4m3 byte
  int r = __builtin_amdgcn_cvt_pk_fp8_f32(v, v, 0, false);
  return (unsigned char)(r & 0xff);
}
DEVFN unsigned pk4_fp8(float a, float b, float c, float d){  // bytes [a,b,c,d]
  int r = __builtin_amdgcn_cvt_pk_fp8_f32(a, b, 0, false);
  r = __builtin_amdgcn_cvt_pk_fp8_f32(c, d, r, true);
  return (unsigned)r;
}
DEVFN long mk64(unsigned lo, unsigned hi){
  return (long)(((unsigned long long)hi << 32) | lo);
}

DEVFN void gload16(const char* src, char* lds){
  __builtin_amdgcn_global_load_lds(
      (__attribute__((address_space(1))) void*)src,
      (__attribute__((address_space(3))) void*)lds, 16, 0, 0);
}

constexpr int BB = 16, NQ = 2048, NK = 2048, F = 512, D = 256, FV = 512;

// ---------------- projection + row l2norm -> fp8 outputs (merged, dbuf) ----------
// Y[m][n] = scale * l2norm_rows( X[m][:] . W[n][:] ), 32 rows/block-slice.
// MODE 0: row-major fp8 [row][ND] (wq)          KD=512 ND=256, dbuf 1-barrier
// MODE 1: K frag-image  [b][kt][u][lane][16]    KD=256 ND=256, dbuf 1-barrier
// MODE 2: V frag-image  (transposed)            KD=256 ND=512, sbuf 2-barrier
// Epilogues: byte-scatter into LDS, then dense coalesced b128 global stores.
template<int KD, int ND, int MODE>
DEVFN void proj_body(const float* __restrict__ X, const float* __restrict__ W,
                     unsigned char* __restrict__ Y, float scale,
                     char* sm, float (*wsum)[32], int bid)
{
  constexpr bool TR = (MODE == 2);
  constexpr int NW = ND/4;
  constexpr int AF = TR ? 8 : 2;
  constexpr int BF = TR ? 2 : NW/16;
  constexpr int NIT = KD/32;
  const int tid = threadIdx.x;
  const int lane = tid & 63;
  const int wid = tid >> 6;
  const int q16 = lane & 15;
  const int g = lane >> 4;
  const int row0 = bid * 32;
  const int rX = tid >> 3, cX = (tid & 7) * 4;

  f32x4 z4 = {0.f,0.f,0.f,0.f};
  f32x4 acc[AF][BF];
  #pragma unroll
  for (int i=0;i<AF;i++){
    #pragma unroll
    for (int j=0;j<BF;j++) acc[i][j] = z4;
  }

  // T14 async-stage: preload k0=0
  f32x4 xr = *(const f32x4*)(X + (size_t)(row0+rX)*KD + cX);
  f32x4 wr[ND/32];
  #pragma unroll
  for (int j=0;j<ND/32;j++)
    wr[j] = *(const f32x4*)(W + (size_t)(j*32+rX)*KD + cX);

  for (int t = 0; t < NIT; ++t){
    char* xb; char* wb;
    if constexpr (TR){ xb = sm; wb = sm + 2560; }           // single buffer
    else { xb = sm + (t&1)*23040; wb = xb + 2560; }         // double buffer
    {
      u32x2 p; p[0]=cvtpk(xr[0],xr[1]); p[1]=cvtpk(xr[2],xr[3]);
      *(u32x2*)(xb + rX*80 + cX*2) = p;
    }
    #pragma unroll
    for (int j=0;j<ND/32;j++){
      u32x2 p; p[0]=cvtpk(wr[j][0],wr[j][1]); p[1]=cvtpk(wr[j][2],wr[j][3]);
      *(u32x2*)(wb + (j*32+rX)*80 + cX*2) = p;
    }
    if (t + 1 < NIT){   // issue next-step loads; latency hides under MFMA
      int k0n = (t+1)*32;
      xr = *(const f32x4*)(X + (size_t)(row0+rX)*KD + k0n + cX);
      #pragma unroll
      for (int j=0;j<ND/32;j++)
        wr[j] = *(const f32x4*)(W + (size_t)(j*32+rX)*KD + k0n + cX);
    }
    __syncthreads();
    if constexpr (!TR){
      bf16x8 a[2], bb[BF];
      #pragma unroll
      for (int mi=0;mi<2;mi++)  a[mi]  = as_bf(*(const u32x4*)(xb + (16*mi+q16)*80 + g*16));
      #pragma unroll
      for (int ni=0;ni<BF;ni++) bb[ni] = as_bf(*(const u32x4*)(wb + (wid*NW + 16*ni + q16)*80 + g*16));
      #pragma unroll
      for (int mi=0;mi<2;mi++){
        #pragma unroll
        for (int ni=0;ni<BF;ni++)
          acc[mi][ni] = __builtin_amdgcn_mfma_f32_16x16x32_bf16(a[mi], bb[ni], acc[mi][ni], 0,0,0);
      }
      // dbuf: next iter writes the OTHER buffer; reads drain at next barrier.
    } else {
      bf16x8 a[8], bb[2];
      #pragma unroll
      for (int ai=0;ai<8;ai++) a[ai] = as_bf(*(const u32x4*)(wb + (wid*NW + 16*ai + q16)*80 + g*16));
      #pragma unroll
      for (int ci=0;ci<2;ci++) bb[ci] = as_bf(*(const u32x4*)(xb + (16*ci+q16)*80 + g*16));
      #pragma unroll
      for (int ai=0;ai<8;ai++){
        #pragma unroll
        for (int ci=0;ci<2;ci++)
          acc[ai][ci] = __builtin_amdgcn_mfma_f32_16x16x32_bf16(a[ai], bb[ci], acc[ai][ci], 0,0,0);
      }
      __syncthreads();   // single buffer: protect before next write
    }
  }

  unsigned char* lds8 = (unsigned char*)sm;

  if constexpr (!TR){
    float part[2][4];
    #pragma unroll
    for (int mi=0;mi<2;mi++){
      #pragma unroll
      for (int r=0;r<4;r++){
        float s=0.f;
        #pragma unroll
        for (int ni=0;ni<BF;ni++){ float v=acc[mi][ni][r]; s += v*v; }
        part[mi][r]=s;
      }
    }
    #pragma unroll
    for (int m=1;m<16;m<<=1){
      #pragma unroll
      for (int mi=0;mi<2;mi++){
        #pragma unroll
        for (int r=0;r<4;r++) part[mi][r] += __shfl_xor(part[mi][r], m);
      }
    }
    __syncthreads();   // drain last-iter LDS reads before sm reuse / wsum
    if (q16 == 0){
      #pragma unroll
      for (int mi=0;mi<2;mi++){
        #pragma unroll
        for (int r=0;r<4;r++) wsum[wid][16*mi + 4*g + r] = part[mi][r];
      }
    }
    __syncthreads();
    // scatter bytes into LDS [8KB]
    #pragma unroll
    for (int mi=0;mi<2;mi++){
      #pragma unroll
      for (int r=0;r<4;r++){
        int m = 16*mi + 4*g + r;
        float tot = wsum[0][m]+wsum[1][m]+wsum[2][m]+wsum[3][m];
        float inv = scale / fmaxf(sqrtf(tot), 1e-12f);
        #pragma unroll
        for (int ni=0;ni<BF;ni++){
          int col = wid*NW + 16*ni + q16;
          unsigned char vb = f2fp8(acc[mi][ni][r]*inv);
          if constexpr (MODE == 0){
            lds8[m*256 + col] = vb;
          } else {
            int u = col >> 5, dd = col & 31;
            int s = ((dd>>4)<<3) | (dd&7);
            int l = (m & 31) + ((dd>>3)&1)*32;
            lds8[(u*64 + l)*16 + s] = vb;
          }
        }
      }
    }
    __syncthreads();
    // dense coalesced writeout: 8KB = 2 passes x 256 thr x 16B
    unsigned char* dst;
    if constexpr (MODE == 0){
      dst = Y + (size_t)row0*256;
    } else {
      int b2 = row0 >> 11, kt = (row0 & 2047) >> 5;
      dst = Y + (((size_t)b2*64 + kt)*8192);
    }
    #pragma unroll
    for (int pass=0; pass<2; ++pass){
      int off = pass*4096 + tid*16;
      *(u32x4*)(dst + off) = *(const u32x4*)(lds8 + off);
    }
  } else {
    float pp[2];
    #pragma unroll
    for (int ci=0;ci<2;ci++){
      float s=0.f;
      #pragma unroll
      for (int ai=0;ai<8;ai++){
        #pragma unroll
        for (int r=0;r<4;r++){ float v=acc[ai][ci][r]; s += v*v; }
      }
      pp[ci]=s;
    }
    #pragma unroll
    for (int ci=0;ci<2;ci++){
      pp[ci] += __shfl_xor(pp[ci],16);
      pp[ci] += __shfl_xor(pp[ci],32);
    }
    if (lane < 16){ wsum[wid][lane] = pp[0]; wsum[wid][16+lane] = pp[1]; }
    __syncthreads();
    // scatter bytes into LDS [16KB]: addr = (fvb*2+ci)*512 + l31v*16 + q16
    #pragma unroll
    for (int ci=0;ci<2;ci++){
      int m = 16*ci + q16;
      float tot = wsum[0][m]+wsum[1][m]+wsum[2][m]+wsum[3][m];
      float inv = scale / fmaxf(sqrtf(tot), 1e-12f);
      #pragma unroll
      for (int ai=0;ai<8;ai++){
        #pragma unroll
        for (int r=0;r<4;r++){
          int n = wid*NW + 16*ai + 4*g + r;
          int fvb = n >> 5, l31v = n & 31;
          unsigned char vb = f2fp8(acc[ai][ci][r]*inv);
          lds8[(fvb*2 + ci)*512 + l31v*16 + q16] = vb;
        }
      }
    }
    __syncthreads();
    // dense writeout: 16KB in 4 passes x 256 thr x 16B; chunk = 512B
    int b2 = row0 >> 11;
    int kvv = row0 & 2047;
    int t64 = kvv >> 6, hh = (kvv >> 5) & 1;
    unsigned char* vbase = Y + ((size_t)b2*32 + t64)*32768;
    #pragma unroll
    for (int pass=0; pass<4; ++pass){
      int L = pass*4096 + tid*16;
      int c = L >> 9, inner = L & 511;
      unsigned char* dst = vbase + (size_t)(c>>1)*2048 + (c&1)*1024 + hh*512 + inner;
      *(u32x4*)dst = *(const u32x4*)(lds8 + L);
    }
  }
}

__global__ __launch_bounds__(256,2) void proj_all(
    const float* __restrict__ query, const float* __restrict__ key,
    const float* __restrict__ value, const float* __restrict__ WQ,
    const float* __restrict__ WK, const float* __restrict__ WV,
    unsigned char* __restrict__ wq8, unsigned char* __restrict__ k8,
    unsigned char* __restrict__ v8, float sq)
{
  __shared__ __align__(16) char sm[46080];   // max(dbuf 2x23040, sbuf 43520)
  __shared__ float wsum[4][32];
  const int bid = blockIdx.x;
  if (bid < 1024){
    proj_body<512,256,0>(query, WQ, wq8, sq,   sm, wsum, bid);
  } else if (bid < 2048){
    proj_body<256,256,1>(key,   WK, k8,  8.0f, sm, wsum, bid - 1024);
  } else {
    proj_body<256,512,2>(value, WV, v8,  8.0f, sm, wsum, bid - 2048);
  }
}

// ---------------- fused attention (v10: fp8 K=16, kv-tile 64, exp-split) --------
// (R10 verbatim — 97.5 us, MfmaUtil 43%, no spill; frozen)
__global__ __launch_bounds__(512,2) void attn_kernel(const float* __restrict__ query,
    const unsigned char* __restrict__ wq8, const unsigned char* __restrict__ k8,
    const unsigned char* __restrict__ v8, float* __restrict__ out)
{
  // K dbuf 2x16K @0 | V dbuf 2x32K @32768 | P 8K @98304. Epilogue reuses 64K.
  __shared__ __align__(16) char smem[106496];
  const int tid = threadIdx.x, lane = tid & 63, wid = tid >> 6;
  const int l31 = lane & 31, h = lane >> 5;
  const int qs = wid & 3, fvh = wid >> 2;
  const int bid = blockIdx.x;
  const int lb = (bid & 7)*32 + (bid >> 3);   // XCD chunk swizzle, 256 = 8*32 bijective
  const int b = lb >> 4;
  const int qblk = lb & 15;
  const int q0 = qblk*128;

  const char* ksrc = (const char*)(k8 + (size_t)b*524288)  + lane*16;
  const char* vsrc = (const char*)(v8 + (size_t)b*1048576) + lane*16;
  char* const pwav = smem + 98304 + qs*2048;   // [s 2][row 8][q 32] dwords

  #define STAGE(T, CUR) do{                                                  \
    gload16(ksrc + (size_t)(T)*16384 + (2*wid  )*1024,                       \
            smem + (CUR)*16384 + (2*wid  )*1024);                            \
    gload16(ksrc + (size_t)(T)*16384 + (2*wid+1)*1024,                       \
            smem + (CUR)*16384 + (2*wid+1)*1024);                            \
    _Pragma("unroll")                                                        \
    for (int i_=0;i_<4;i_++)                                                 \
      gload16(vsrc + (size_t)(T)*32768 + (4*wid+i_)*1024,                    \
              smem + 32768 + (CUR)*32768 + (4*wid+i_)*1024);                 \
  }while(0)

  STAGE(0, 0);

  // Q hoist: fp8 B-frags [16 c][32 q]: lane q=l31, bytes d = c*16 + h*8 ..+8
  unsigned long long qf[16];
  {
    const unsigned char* qb = wq8 + ((size_t)b*NQ + q0 + qs*32 + l31)*D;
    #pragma unroll
    for (int c=0;c<16;c++) qf[c] = *(const unsigned long long*)(qb + c*16 + h*8);
  }

  f32x16 z16;
  #pragma unroll
  for (int i=0;i<16;i++) z16[i]=0.f;
  f32x16 o[8];
  #pragma unroll
  for (int i=0;i<8;i++) o[i]=z16;
  float ssum = 0.f;
  const float c2 = 0.0625f * 1.4426950408889634f / 64.0f;   // temp*log2e/(8*8)

  __syncthreads();

  #define BODY(T, CUR) do{                                                          \
    if ((T) < 31) STAGE((T)+1, (CUR)^1);                                            \
    /* QK on own kv-sub-tile (kt = 2T + fvh) */                                     \
    const char* kb = smem + (CUR)*16384 + fvh*8192;                                 \
    f32x16 S = z16;                                                                 \
    __builtin_amdgcn_s_setprio(1);                                                  \
    _Pragma("unroll")                                                               \
    for (int u=0;u<8;u++){                                                          \
      u32x4 kk = *(const u32x4*)(kb + u*1024 + lane*16);                            \
      S = __builtin_amdgcn_mfma_f32_32x32x16_fp8_fp8(mk64(kk[0],kk[1]),             \
            (long)qf[2*u],   S, 0,0,0);                                             \
      S = __builtin_amdgcn_mfma_f32_32x32x16_fp8_fp8(mk64(kk[2],kk[3]),             \
            (long)qf[2*u+1], S, 0,0,0);                                             \
    }                                                                               \
    __builtin_amdgcn_s_setprio(0);                                                  \
    float p[16];                                                                    \
    _Pragma("unroll")                                                               \
    for (int r=0;r<16;r++) p[r] = exp2_hw(S[r]*c2);                                 \
    {                                                                               \
      float s2a = (p[0]+p[1])+(p[2]+p[3]),  s2b = (p[4]+p[5])+(p[6]+p[7]);          \
      float s2c = (p[8]+p[9])+(p[10]+p[11]), s2d = (p[12]+p[13])+(p[14]+p[15]);     \
      ssum += (s2a+s2b) + (s2c+s2d);                                                \
    }                                                                               \
    /* pack P -> LDS: dword m covers kv_local 8m+4h..+3 ; row = m*2+h */            \
    _Pragma("unroll")                                                               \
    for (int m=0;m<4;m++){                                                          \
      unsigned dw = pk4_fp8(p[4*m],p[4*m+1],p[4*m+2],p[4*m+3]);                     \
      *(unsigned*)(pwav + fvh*1024 + (m*2+h)*128 + l31*4) = dw;                     \
    }                                                                               \
    __syncthreads();   /* P visible; staging (issued at top) drains */              \
    __builtin_amdgcn_s_setprio(1);                                                  \
    _Pragma("unroll")                                                               \
    for (int s=0;s<2;s++){                                                          \
      unsigned lo0 = *(const unsigned*)(pwav + s*1024 + ((0+h)*2  )*128 + l31*4);   \
      unsigned hi0 = *(const unsigned*)(pwav + s*1024 + ((0+h)*2+1)*128 + l31*4);   \
      unsigned lo1 = *(const unsigned*)(pwav + s*1024 + ((2+h)*2  )*128 + l31*4);   \
      unsigned hi1 = *(const unsigned*)(pwav + s*1024 + ((2+h)*2+1)*128 + l31*4);   \
      long B0 = mk64(lo0, hi0), B1 = mk64(lo1, hi1);                                \
      const char* vb = smem + 32768 + (CUR)*32768 + s*16384 + fvh*8192;             \
      _Pragma("unroll")                                                             \
      for (int u=0;u<8;u++){                                                        \
        u32x4 vv = *(const u32x4*)(vb + u*1024 + lane*16);                          \
        o[u] = __builtin_amdgcn_mfma_f32_32x32x16_fp8_fp8(mk64(vv[0],vv[1]), B0,    \
                                                          o[u], 0,0,0);             \
        o[u] = __builtin_amdgcn_mfma_f32_32x32x16_fp8_fp8(mk64(vv[2],vv[3]), B1,    \
                                                          o[u], 0,0,0);             \
      }                                                                             \
    }                                                                               \
    __builtin_amdgcn_s_setprio(0);                                                  \
    __syncthreads();   /* tile handoff; protects P for next write */                \
  }while(0)

  for (int tt = 0; tt < 32; tt += 2){
    BODY(tt,   0);
    BODY(tt+1, 1);
  }
  #undef BODY
  #undef STAGE

  // ssum: + h-partner (in-wave), then + fvh-partner wave (via LDS, post-loop reuse)
  ssum += __shfl_xor(ssum, 32);
  {
    float* sx = (float*)(smem + 98304);
    sx[(qs*2+fvh)*32 + l31] = ssum;
    __syncthreads();
    ssum += sx[(qs*2+(1-fvh))*32 + l31];
  }
  const float inv = 1.f/(8.f*ssum);
  #pragma unroll
  for (int i=0;i<8;i++){
    #pragma unroll
    for (int r=0;r<16;r++) o[i][r] *= inv;
  }

  // epilogue: transpose via LDS [32q][128fv] x2 per qs, +query, store.
  char* wsc = smem + qs*16384;
  union U16 { f32x16 v; f32x4 q4[4]; };
  const int swz = (l31 & 7) << 4;
  #pragma unroll
  for (int phase=0; phase<2; ++phase){
    if (fvh == phase){
      #pragma unroll
      for (int hf=0; hf<2; ++hf){
        #pragma unroll
        for (int fc2=0; fc2<4; ++fc2){
          U16 u; u.v = o[hf*4+fc2];
          #pragma unroll
          for (int k=0;k<4;k++){
            *(f32x4*)(wsc + l31*512 + ((fc2*128 + k*32 + h*16) ^ swz)) = u.q4[k];
          }
        }
        #pragma unroll
        for (int p2=0;p2<16;p2++){
          int qr = p2*2 + h;
          f32x4 v = *(const f32x4*)(wsc + qr*512 + ((l31*16) ^ ((qr&7)<<4)));
          size_t row = (size_t)b*NQ + q0 + qs*32 + qr;
          int col = fvh*256 + hf*128 + l31*4;
          f32x4 qv = *(const f32x4*)(query + row*F + col);
          #pragma unroll
          for (int e=0;e<4;e++) v[e] += qv[e];
          *(f32x4*)(out + row*F + col) = v;
        }
      }
    }
    __syncthreads();
  }
}

extern "C" void kernel_launch(void* const* d_in, const int* in_sizes, int n_in,
                              void* d_out, int out_size, void* d_ws, size_t ws_size,
                              hipStream_t stream)
{
  const float* query = (const float*)d_in[0];
  const float* key   = (const float*)d_in[1];
  const float* value = (const float*)d_in[2];
  const float* WQ    = (const float*)d_in[3];
  const float* WK    = (const float*)d_in[4];
  const float* WV    = (const float*)d_in[5];
  float* out = (float*)d_out;

  unsigned char* wq8 = (unsigned char*)d_ws;                 // [B*NQ][256] fp8, 8MB
  unsigned char* k8  = wq8 + (size_t)BB*NQ*D;                // K frag-image, 8MB
  unsigned char* v8  = k8  + (size_t)BB*NK*D;                // V frag-image, 16MB

  proj_all<<<3072, dim3(256), 0, stream>>>(query, key, value, WQ, WK, WV,
                                           wq8, k8, v8, 8.0f);
  attn_kernel<<<256, dim3(512), 0, stream>>>(query, wq8, k8, v8, out);
}